// Round 4
// baseline (910.918 us; speedup 1.0000x reference)
//
#include <hip/hip_runtime.h>
#include <stdint.h>

#define Bb 8
#define Ss 4096
#define Dd 1024
#define Mm (Bb*Ss)      // 32768 rows
#define Kk 1024

typedef _Float16 half8 __attribute__((ext_vector_type(8)));
typedef _Float16 half4v __attribute__((ext_vector_type(4)));
typedef float f32x4 __attribute__((ext_vector_type(4)));

#define LO_SCALE 2048.0f
#define INV_LO_SCALE (1.0f/2048.0f)

__device__ __forceinline__ void gld_lds16(const void* g, void* l) {
  __builtin_amdgcn_global_load_lds(
      (const __attribute__((address_space(1))) unsigned int*)g,
      (__attribute__((address_space(3))) unsigned int*)l, 16, 0, 0);
}

// ---------------- combined split for G / Wq / Wk (grid.y selects src) --------
__global__ void split_w3(const float* __restrict__ G, const float* __restrict__ Wq,
                         const float* __restrict__ Wk,
                         _Float16* __restrict__ Gh, _Float16* __restrict__ Gl,
                         _Float16* __restrict__ Wh, _Float16* __restrict__ Wl) {
  const int which = blockIdx.y;
  const float* src = (which == 0) ? G : (which == 1) ? Wq : Wk;
  _Float16* hi = (which == 0) ? Gh : (which == 1) ? Wh : Wh + (size_t)Dd * Dd;
  _Float16* lo = (which == 0) ? Gl : (which == 1) ? Wl : Wl + (size_t)Dd * Dd;
  const int i = blockIdx.x * 256 + threadIdx.x;   // < Dd*Dd/4
  float4 v = ((const float4*)src)[i];
  _Float16 h0 = (_Float16)v.x, h1 = (_Float16)v.y, h2 = (_Float16)v.z, h3 = (_Float16)v.w;
  _Float16 l0 = (_Float16)((v.x - (float)h0) * LO_SCALE);
  _Float16 l1 = (_Float16)((v.y - (float)h1) * LO_SCALE);
  _Float16 l2 = (_Float16)((v.z - (float)h2) * LO_SCALE);
  _Float16 l3 = (_Float16)((v.w - (float)h3) * LO_SCALE);
  ((half4v*)hi)[i] = (half4v){h0, h1, h2, h3};
  ((half4v*)lo)[i] = (half4v){l0, l1, l2, l3};
}

// ---------------- X split (wave/row) + a_u = u.x, a_v = v.x ------------------
__global__ void split_x(const float* __restrict__ X, const float* __restrict__ u,
                        const float* __restrict__ v,
                        _Float16* __restrict__ Xh, _Float16* __restrict__ Xl,
                        float* __restrict__ a_u, float* __restrict__ a_v) {
  const int s = blockIdx.x * 4 + (threadIdx.x >> 6);
  const int lane = threadIdx.x & 63;
  float au = 0.f, av = 0.f;
#pragma unroll
  for (int c = 0; c < 4; ++c) {
    const int e = c * 256 + lane * 4;
    float4 xv = *(const float4*)&X[(size_t)s * Dd + e];
    float4 uv = *(const float4*)&u[e];
    float4 vv = *(const float4*)&v[e];
    _Float16 h0 = (_Float16)xv.x, h1 = (_Float16)xv.y, h2 = (_Float16)xv.z, h3 = (_Float16)xv.w;
    _Float16 l0 = (_Float16)((xv.x - (float)h0) * LO_SCALE);
    _Float16 l1 = (_Float16)((xv.y - (float)h1) * LO_SCALE);
    _Float16 l2 = (_Float16)((xv.z - (float)h2) * LO_SCALE);
    _Float16 l3 = (_Float16)((xv.w - (float)h3) * LO_SCALE);
    *(half4v*)&Xh[(size_t)s * Dd + e] = (half4v){h0, h1, h2, h3};
    *(half4v*)&Xl[(size_t)s * Dd + e] = (half4v){l0, l1, l2, l3};
    au += uv.x * xv.x + uv.y * xv.y + uv.z * xv.z + uv.w * xv.w;
    av += vv.x * xv.x + vv.y * xv.y + vv.z * xv.z + vv.w * xv.w;
  }
#pragma unroll
  for (int off = 32; off > 0; off >>= 1) {
    au += __shfl_xor(au, off);
    av += __shfl_xor(av, off);
  }
  if (lane == 0) { a_u[s] = au; a_v[s] = av; }
}

// ---------------- G = Wq^T * Wk (fp32 vector GEMM, 64x64 tiles) --------------
__global__ __launch_bounds__(256)
void gemm_g(const float* __restrict__ Wq, const float* __restrict__ Wk,
            float* __restrict__ G) {
  __shared__ float As[16][64];
  __shared__ float Bs[16][64];
  const int t = threadIdx.x;
  const int m0 = blockIdx.y * 64, n0 = blockIdx.x * 64;
  float acc[4][4];
#pragma unroll
  for (int a = 0; a < 4; ++a)
#pragma unroll
    for (int b = 0; b < 4; ++b) acc[a][b] = 0.f;
  for (int kc = 0; kc < 64; ++kc) {
    const int k0 = kc * 16;
#pragma unroll
    for (int l = 0; l < 4; ++l) {
      const int idx = l * 256 + t;
      const int kk = idx >> 6, mm = idx & 63;
      As[kk][mm] = Wq[(size_t)(k0 + kk) * Dd + m0 + mm];
      Bs[kk][mm] = Wk[(size_t)(k0 + kk) * Dd + n0 + mm];
    }
    __syncthreads();
    const int tm = (t & 15) * 4, tn = (t >> 4) * 4;
#pragma unroll
    for (int k = 0; k < 16; ++k) {
      float4 a4 = *(const float4*)&As[k][tm];
      float4 b4 = *(const float4*)&Bs[k][tn];
      const float aa[4] = {a4.x, a4.y, a4.z, a4.w};
      const float bb[4] = {b4.x, b4.y, b4.z, b4.w};
#pragma unroll
      for (int a = 0; a < 4; ++a)
#pragma unroll
        for (int b = 0; b < 4; ++b) acc[a][b] += aa[a] * bb[b];
    }
    __syncthreads();
  }
  const int tm = (t & 15) * 4, tn = (t >> 4) * 4;
#pragma unroll
  for (int a = 0; a < 4; ++a)
#pragma unroll
    for (int b = 0; b < 4; ++b)
      G[(size_t)(m0 + tm + a) * Dd + n0 + tn + b] = acc[a][b];
}

// ------- u[d]=sum_e bq[e]Wk[e,d]; v[d]=sum_e bk[e]Wq[e,d]; c=bq.bk -----------
__global__ void uvc_pass(const float* __restrict__ Wq, const float* __restrict__ Wk,
                         const float* __restrict__ bq, const float* __restrict__ bk,
                         float* __restrict__ u, float* __restrict__ v,
                         float* __restrict__ c) {
  const int bx = blockIdx.x;
  if (bx == 8) {
    const int lane = threadIdx.x;
    if (lane >= 64) return;
    float a = 0.f;
#pragma unroll
    for (int i = 0; i < 16; ++i) a += bq[lane * 16 + i] * bk[lane * 16 + i];
#pragma unroll
    for (int off = 32; off > 0; off >>= 1) a += __shfl_xor(a, off);
    if (lane == 0) *c = a;
    return;
  }
  const int which = bx >> 2;                    // 0 -> u, 1 -> v
  const int d = (bx & 3) * 256 + threadIdx.x;
  const float* W = which ? Wq : Wk;
  const float* bb = which ? bk : bq;
  float acc = 0.f;
#pragma unroll 4
  for (int e = 0; e < Dd; ++e) acc += bb[e] * W[(size_t)e * Dd + d];
  if (which) v[d] = acc; else u[d] = acc;
}

// ---------------- fused MFMA kernel ------------------------------------------
// blockIdx.x in [0,8):  dot path  — split GEMM X*G^T (hh+hl+lh), epilogue
//                       computes partial x_{s+1}.y_s into pd (no Y write).
// blockIdx.x in [8,24): norm path — hh GEMM X*[Wq;Wk]^T, epilogue reduces
//                       row sum-of-squares into pn.
// NOTE: (256,2) launch bounds — dot path's accH+accX alone are 128 unified
// regs/thread; (256,4) forces spills (round 2: WRITE 3.4 GB, MfmaUtil 6%).
__global__ __launch_bounds__(256, 2)
void gemm_fused(const _Float16* __restrict__ Ah, const _Float16* __restrict__ Al,
                const _Float16* __restrict__ Gh, const _Float16* __restrict__ Gl,
                const _Float16* __restrict__ Wh,
                const float* __restrict__ X,
                const float* __restrict__ bq, const float* __restrict__ bk,
                float* __restrict__ pd, float* __restrict__ pn) {
  __shared__ __align__(16) _Float16 AsH[128 * 32];
  __shared__ __align__(16) _Float16 AsL[128 * 32];
  __shared__ __align__(16) _Float16 BsH[128 * 32];
  __shared__ __align__(16) _Float16 BsL[128 * 32];
  const int tid = threadIdx.x;
  const int wave = tid >> 6, lane = tid & 63;
  const int m0 = blockIdx.y * 128;
  const int wm = (wave >> 1) * 64, wn = (wave & 1) * 64;
  const int srow = lane >> 2, c8 = lane & 3;
  const int fr = lane & 15, g = lane >> 4;

  if (blockIdx.x < 8) {
    // ---------------- dot path ----------------
    const int n0 = blockIdx.x * 128;
    f32x4 accH[4][4], accX[4][4];
#pragma unroll
    for (int i = 0; i < 4; ++i)
#pragma unroll
      for (int j = 0; j < 4; ++j) {
        accH[i][j] = (f32x4){0.f, 0.f, 0.f, 0.f};
        accX[i][j] = (f32x4){0.f, 0.f, 0.f, 0.f};
      }
    for (int kt = 0; kt < Kk / 32; ++kt) {
      const int k0 = kt * 32;
#pragma unroll
      for (int it = 0; it < 2; ++it) {
        const int R = wave * 32 + it * 16 + srow;
        const int sg = c8 ^ ((R >> 2) & 3);
        const int ldsoff = (wave * 32 + it * 16) * 32;
        const size_t ga = (size_t)(m0 + R) * Kk + k0 + sg * 8;
        const size_t gb = (size_t)(n0 + R) * Kk + k0 + sg * 8;
        gld_lds16(Ah + ga, &AsH[ldsoff]);
        gld_lds16(Al + ga, &AsL[ldsoff]);
        gld_lds16(Gh + gb, &BsH[ldsoff]);
        gld_lds16(Gl + gb, &BsL[ldsoff]);
      }
      __syncthreads();
      half8 bh[4], bl[4];
#pragma unroll
      for (int j = 0; j < 4; ++j) {
        const int R = wn + 16 * j + fr;
        const int slot = g ^ ((R >> 2) & 3);
        bh[j] = *(const half8*)&BsH[R * 32 + slot * 8];
        bl[j] = *(const half8*)&BsL[R * 32 + slot * 8];
      }
#pragma unroll
      for (int i = 0; i < 4; ++i) {
        const int R = wm + 16 * i + fr;
        const int slot = g ^ ((R >> 2) & 3);
        half8 ah = *(const half8*)&AsH[R * 32 + slot * 8];
        half8 al = *(const half8*)&AsL[R * 32 + slot * 8];
#pragma unroll
        for (int j = 0; j < 4; ++j) {
          accH[i][j] = __builtin_amdgcn_mfma_f32_16x16x32_f16(ah, bh[j], accH[i][j], 0, 0, 0);
          accX[i][j] = __builtin_amdgcn_mfma_f32_16x16x32_f16(ah, bl[j], accX[i][j], 0, 0, 0);
          accX[i][j] = __builtin_amdgcn_mfma_f32_16x16x32_f16(al, bh[j], accX[i][j], 0, 0, 0);
        }
      }
      __syncthreads();
    }
    // epilogue: partial dot d_t += x_t . y_{t-1} over this block's 64 cols
    const int quad = lane >> 4;
    const int slot = blockIdx.x * 2 + (wave & 1);
#pragma unroll
    for (int i = 0; i < 4; ++i) {
#pragma unroll
      for (int r = 0; r < 4; ++r) {
        const int s = m0 + wm + 16 * i + quad * 4 + r;
        const int t = s + 1;
        float dsum = 0.f;
        if ((t & (Ss - 1)) != 0) {
          const float* xrow = X + (size_t)t * Dd + n0 + wn;
#pragma unroll
          for (int j = 0; j < 4; ++j) {
            float yv = accH[i][j][r] + accX[i][j][r] * INV_LO_SCALE;
            dsum += yv * xrow[16 * j + fr];
          }
        }
        dsum += __shfl_xor(dsum, 1);
        dsum += __shfl_xor(dsum, 2);
        dsum += __shfl_xor(dsum, 4);
        dsum += __shfl_xor(dsum, 8);
        if (fr == 0 && ((t & (Ss - 1)) != 0))
          pd[(size_t)slot * Mm + t] = dsum;
      }
    }
  } else {
    // ---------------- norm path ----------------
    const int n0 = (blockIdx.x - 8) * 128;
    f32x4 acc[4][4];
#pragma unroll
    for (int i = 0; i < 4; ++i)
#pragma unroll
      for (int j = 0; j < 4; ++j) acc[i][j] = (f32x4){0.f, 0.f, 0.f, 0.f};
    for (int kt = 0; kt < Kk / 32; ++kt) {
      const int k0 = kt * 32;
#pragma unroll
      for (int it = 0; it < 2; ++it) {
        const int R = wave * 32 + it * 16 + srow;
        const int sg = c8 ^ ((R >> 2) & 3);
        const int ldsoff = (wave * 32 + it * 16) * 32;
        gld_lds16(Ah + (size_t)(m0 + R) * Kk + k0 + sg * 8, &AsH[ldsoff]);
        gld_lds16(Wh + (size_t)(n0 + R) * Kk + k0 + sg * 8, &BsH[ldsoff]);
      }
      __syncthreads();
      half8 bh[4];
#pragma unroll
      for (int j = 0; j < 4; ++j) {
        const int R = wn + 16 * j + fr;
        const int slot = g ^ ((R >> 2) & 3);
        bh[j] = *(const half8*)&BsH[R * 32 + slot * 8];
      }
#pragma unroll
      for (int i = 0; i < 4; ++i) {
        const int R = wm + 16 * i + fr;
        const int slot = g ^ ((R >> 2) & 3);
        half8 ah = *(const half8*)&AsH[R * 32 + slot * 8];
#pragma unroll
        for (int j = 0; j < 4; ++j)
          acc[i][j] = __builtin_amdgcn_mfma_f32_16x16x32_f16(ah, bh[j], acc[i][j], 0, 0, 0);
      }
      __syncthreads();
    }
    const int quad = lane >> 4;
    float bias_j[4];
#pragma unroll
    for (int j = 0; j < 4; ++j) {
      const int n = n0 + wn + 16 * j + fr;
      bias_j[j] = (n < Dd) ? bq[n] : bk[n - Dd];
    }
    const int slot = (blockIdx.x - 8) * 2 + (wave & 1);
#pragma unroll
    for (int i = 0; i < 4; ++i) {
#pragma unroll
      for (int r = 0; r < 4; ++r) {
        float vsum = 0.f;
#pragma unroll
        for (int j = 0; j < 4; ++j) {
          float q = acc[i][j][r] + bias_j[j];
          vsum += q * q;
        }
        vsum += __shfl_xor(vsum, 1);
        vsum += __shfl_xor(vsum, 2);
        vsum += __shfl_xor(vsum, 4);
        vsum += __shfl_xor(vsum, 8);
        if (fr == 0)
          pn[(size_t)slot * Mm + (m0 + wm + 16 * i + quad * 4 + r)] = vsum;
      }
    }
  }
}

// ---------------- final cos / p / b (thread per row) -------------------------
__global__ void cos_final(const float* __restrict__ pd, const float* __restrict__ pn,
                          const float* __restrict__ a_u, const float* __restrict__ a_v,
                          const float* __restrict__ cptr,
                          float* __restrict__ p_out, float* __restrict__ b_out) {
  const int s = blockIdx.x * 256 + threadIdx.x;
  if ((s & (Ss - 1)) == 0) { p_out[s] = 1.0f; b_out[s] = 1.0f; return; }
  float dot = a_u[s - 1] + a_v[s] + *cptr;
#pragma unroll
  for (int sl = 0; sl < 16; ++sl) dot += pd[(size_t)sl * Mm + s];
  float nq = 0.f, nk = 0.f;
#pragma unroll
  for (int sl = 0; sl < 16; ++sl) nq += pn[(size_t)sl * Mm + s];
#pragma unroll
  for (int sl = 16; sl < 32; ++sl) nk += pn[(size_t)sl * Mm + (s - 1)];
  float denom = fmaxf(sqrtf(nq), 1e-8f) * fmaxf(sqrtf(nk), 1e-8f);
  float cs = dot / denom;
  float p = 0.5f * (1.0f - cs);
  p_out[s] = p;
  b_out[s] = (p >= 0.5f) ? 1.0f : 0.0f;
}

// ---------------- per-batch stable scan of flags -----------------------------
__global__ void scan_flags(const float* __restrict__ b_out,
                           int* __restrict__ sel, int* __restrict__ counts) {
  const int b = blockIdx.x;
  const int tid = threadIdx.x;
  const int lane = tid & 63;
  const int w = tid >> 6;
  __shared__ int wtot[4];
  int running = 0;
  for (int c = 0; c < Ss / 256; ++c) {
    const int i = c * 256 + tid;
    const bool f = b_out[b * Ss + i] != 0.0f;
    unsigned long long m = __ballot(f);
    int pre = __popcll(m & ((1ull << lane) - 1ull));
    if (lane == 0) wtot[w] = __popcll(m);
    __syncthreads();
    int woff = 0;
#pragma unroll
    for (int ww = 0; ww < 4; ++ww)
      if (ww < w) woff += wtot[ww];
    int tot = wtot[0] + wtot[1] + wtot[2] + wtot[3];
    if (f) sel[b * Ss + running + woff + pre] = i;
    running += tot;
    __syncthreads();
  }
  if (tid == 0) counts[b] = running;
}

// ---------------- gather selected rows / zero-fill ---------------------------
__global__ void write_out(const float* __restrict__ x, const int* __restrict__ sel,
                          const int* __restrict__ counts, float* __restrict__ out) {
  const int blk = blockIdx.x;
  const int b = blk >> 12;
  const int r = blk & (Ss - 1);
  const int tid = threadIdx.x;
  float4 v = {0.f, 0.f, 0.f, 0.f};
  if (r < counts[b]) {
    const int src = sel[b * Ss + r];
    v = *(const float4*)&x[((size_t)b * Ss + src) * Dd + tid * 4];
  }
  *(float4*)&out[(size_t)blk * Dd + tid * 4] = v;
}

extern "C" void kernel_launch(void* const* d_in, const int* in_sizes, int n_in,
                              void* d_out, int out_size, void* d_ws, size_t ws_size,
                              hipStream_t stream) {
  const float* x  = (const float*)d_in[0];
  const float* Wq = (const float*)d_in[1];
  const float* bq = (const float*)d_in[2];
  const float* Wk = (const float*)d_in[3];
  const float* bk = (const float*)d_in[4];
  float* out = (float*)d_out;

  uint8_t* w = (uint8_t*)d_ws;
  _Float16* Xh = (_Float16*)w;   w += (size_t)Mm * Kk * 2;     // 64 MB
  _Float16* Xl = (_Float16*)w;   w += (size_t)Mm * Kk * 2;     // 64 MB
  float*    G  = (float*)w;      w += (size_t)Dd * Dd * 4;     // 4 MB
  _Float16* Gh = (_Float16*)w;   w += (size_t)Dd * Dd * 2;     // 2 MB
  _Float16* Gl = (_Float16*)w;   w += (size_t)Dd * Dd * 2;     // 2 MB
  _Float16* Wh = (_Float16*)w;   w += (size_t)2 * Dd * Dd * 2; // 4 MB
  _Float16* Wl = (_Float16*)w;   w += (size_t)2 * Dd * Dd * 2; // 4 MB (unused; kept for layout headroom)
  float* pd = (float*)w;         w += (size_t)16 * Mm * 4;     // 2 MB
  float* pn = (float*)w;         w += (size_t)32 * Mm * 4;     // 4 MB
  float* a_u = (float*)w;        w += (size_t)Mm * 4;
  float* a_v = (float*)w;        w += (size_t)Mm * 4;
  float* u   = (float*)w;        w += Dd * 4;
  float* v   = (float*)w;        w += Dd * 4;
  float* cpt = (float*)w;        w += 64;
  int*   sel = (int*)w;          w += (size_t)Mm * 4;
  int*   counts = (int*)w;       w += 64;
  (void)Wl;

  float* p_out = out + (size_t)Mm * Dd;
  float* b_out = p_out + Mm;

  // prep (independent of X): G = Wq^T Wk, u/v/c
  gemm_g<<<dim3(16, 16), 256, 0, stream>>>(Wq, Wk, G);
  uvc_pass<<<9, 256, 0, stream>>>(Wq, Wk, bq, bk, u, v, cpt);
  // splits
  split_x<<<Mm / 4, 256, 0, stream>>>(x, u, v, Xh, Xl, a_u, a_v);
  split_w3<<<dim3((Dd * Dd / 4) / 256, 3), 256, 0, stream>>>(G, Wq, Wk, Gh, Gl, Wh, Wl);
  // fused dot+norm MFMA pass
  gemm_fused<<<dim3(24, Mm / 128), 256, 0, stream>>>(Xh, Xl, Gh, Gl, Wh, x, bq, bk, pd, pn);
  // epilogue chain
  cos_final<<<Mm / 256, 256, 0, stream>>>(pd, pn, a_u, a_v, cpt, p_out, b_out);
  scan_flags<<<Bb, 256, 0, stream>>>(b_out, sel, counts);
  write_out<<<Mm, 256, 0, stream>>>(x, sel, counts, out);
}

// Round 5
// 781.880 us; speedup vs baseline: 1.1650x; 1.1650x over previous
//
#include <hip/hip_runtime.h>
#include <stdint.h>

#define Bb 8
#define Ss 4096
#define Dd 1024
#define Mm (Bb*Ss)      // 32768 rows
#define Kk 1024

typedef _Float16 half8 __attribute__((ext_vector_type(8)));
typedef _Float16 half4v __attribute__((ext_vector_type(4)));
typedef float f32x4 __attribute__((ext_vector_type(4)));

#define LO_SCALE 2048.0f
#define INV_LO_SCALE (1.0f/2048.0f)

__device__ __forceinline__ void gld_lds16(const void* g, void* l) {
  __builtin_amdgcn_global_load_lds(
      (const __attribute__((address_space(1))) unsigned int*)g,
      (__attribute__((address_space(3))) unsigned int*)l, 16, 0, 0);
}

// ---------------- split for G(sum of 4 partials) / Wq / Wk -------------------
// which==0: G = sum(Gp[0..3]) -> Gh,Gl (hi+lo). which==1/2: Wq/Wk -> Wh (hi only).
__global__ void split_w3(const float* __restrict__ Gp, const float* __restrict__ Wq,
                         const float* __restrict__ Wk,
                         _Float16* __restrict__ Gh, _Float16* __restrict__ Gl,
                         _Float16* __restrict__ Wh) {
  const int which = blockIdx.y;
  const int i = blockIdx.x * 256 + threadIdx.x;   // < Dd*Dd/4
  float4 v;
  if (which == 0) {
    float4 v0 = ((const float4*)Gp)[i];
    float4 v1 = ((const float4*)(Gp + (size_t)Dd * Dd))[i];
    float4 v2 = ((const float4*)(Gp + (size_t)2 * Dd * Dd))[i];
    float4 v3 = ((const float4*)(Gp + (size_t)3 * Dd * Dd))[i];
    v.x = (v0.x + v1.x) + (v2.x + v3.x);
    v.y = (v0.y + v1.y) + (v2.y + v3.y);
    v.z = (v0.z + v1.z) + (v2.z + v3.z);
    v.w = (v0.w + v1.w) + (v2.w + v3.w);
  } else {
    const float* src = (which == 1) ? Wq : Wk;
    v = ((const float4*)src)[i];
  }
  _Float16 h0 = (_Float16)v.x, h1 = (_Float16)v.y, h2 = (_Float16)v.z, h3 = (_Float16)v.w;
  if (which == 0) {
    _Float16 l0 = (_Float16)((v.x - (float)h0) * LO_SCALE);
    _Float16 l1 = (_Float16)((v.y - (float)h1) * LO_SCALE);
    _Float16 l2 = (_Float16)((v.z - (float)h2) * LO_SCALE);
    _Float16 l3 = (_Float16)((v.w - (float)h3) * LO_SCALE);
    ((half4v*)Gh)[i] = (half4v){h0, h1, h2, h3};
    ((half4v*)Gl)[i] = (half4v){l0, l1, l2, l3};
  } else {
    _Float16* hi = (which == 1) ? Wh : Wh + (size_t)Dd * Dd;
    ((half4v*)hi)[i] = (half4v){h0, h1, h2, h3};
  }
}

// ---------------- X split (wave/row) + a_u = u.x, a_v = v.x ------------------
__global__ void split_x(const float* __restrict__ X, const float* __restrict__ u,
                        const float* __restrict__ v,
                        _Float16* __restrict__ Xh, _Float16* __restrict__ Xl,
                        float* __restrict__ a_u, float* __restrict__ a_v) {
  const int s = blockIdx.x * 4 + (threadIdx.x >> 6);
  const int lane = threadIdx.x & 63;
  float au = 0.f, av = 0.f;
#pragma unroll
  for (int c = 0; c < 4; ++c) {
    const int e = c * 256 + lane * 4;
    float4 xv = *(const float4*)&X[(size_t)s * Dd + e];
    float4 uv = *(const float4*)&u[e];
    float4 vv = *(const float4*)&v[e];
    _Float16 h0 = (_Float16)xv.x, h1 = (_Float16)xv.y, h2 = (_Float16)xv.z, h3 = (_Float16)xv.w;
    _Float16 l0 = (_Float16)((xv.x - (float)h0) * LO_SCALE);
    _Float16 l1 = (_Float16)((xv.y - (float)h1) * LO_SCALE);
    _Float16 l2 = (_Float16)((xv.z - (float)h2) * LO_SCALE);
    _Float16 l3 = (_Float16)((xv.w - (float)h3) * LO_SCALE);
    *(half4v*)&Xh[(size_t)s * Dd + e] = (half4v){h0, h1, h2, h3};
    *(half4v*)&Xl[(size_t)s * Dd + e] = (half4v){l0, l1, l2, l3};
    au += uv.x * xv.x + uv.y * xv.y + uv.z * xv.z + uv.w * xv.w;
    av += vv.x * xv.x + vv.y * xv.y + vv.z * xv.z + vv.w * xv.w;
  }
#pragma unroll
  for (int off = 32; off > 0; off >>= 1) {
    au += __shfl_xor(au, off);
    av += __shfl_xor(av, off);
  }
  if (lane == 0) { a_u[s] = au; a_v[s] = av; }
}

// ------- G partial: Gp[z] = Wq[kz]^T * Wk[kz], K-split x4 (G1: 4 blk/CU) -----
__global__ __launch_bounds__(256)
void gemm_g_part(const float* __restrict__ Wq, const float* __restrict__ Wk,
                 float* __restrict__ Gp) {
  __shared__ float As[16][64];
  __shared__ float Bs[16][64];
  const int t = threadIdx.x;
  const int m0 = blockIdx.y * 64, n0 = blockIdx.x * 64;
  const int kbase = blockIdx.z * 256;
  float acc[4][4];
#pragma unroll
  for (int a = 0; a < 4; ++a)
#pragma unroll
    for (int b = 0; b < 4; ++b) acc[a][b] = 0.f;
  for (int kc = 0; kc < 16; ++kc) {
    const int k0 = kbase + kc * 16;
#pragma unroll
    for (int l = 0; l < 4; ++l) {
      const int idx = l * 256 + t;
      const int kk = idx >> 6, mm = idx & 63;
      As[kk][mm] = Wq[(size_t)(k0 + kk) * Dd + m0 + mm];
      Bs[kk][mm] = Wk[(size_t)(k0 + kk) * Dd + n0 + mm];
    }
    __syncthreads();
    const int tm = (t & 15) * 4, tn = (t >> 4) * 4;
#pragma unroll
    for (int k = 0; k < 16; ++k) {
      float4 a4 = *(const float4*)&As[k][tm];
      float4 b4 = *(const float4*)&Bs[k][tn];
      const float aa[4] = {a4.x, a4.y, a4.z, a4.w};
      const float bb[4] = {b4.x, b4.y, b4.z, b4.w};
#pragma unroll
      for (int a = 0; a < 4; ++a)
#pragma unroll
        for (int b = 0; b < 4; ++b) acc[a][b] += aa[a] * bb[b];
    }
    __syncthreads();
  }
  float* dst = Gp + (size_t)blockIdx.z * Dd * Dd;
  const int tm = (t & 15) * 4, tn = (t >> 4) * 4;
#pragma unroll
  for (int a = 0; a < 4; ++a)
#pragma unroll
    for (int b = 0; b < 4; ++b)
      dst[(size_t)(m0 + tm + a) * Dd + n0 + tn + b] = acc[a][b];
}

// ------- u/v partials over e-chunks (32 blocks) + c (block 32) ---------------
__global__ void uvc_part(const float* __restrict__ Wq, const float* __restrict__ Wk,
                         const float* __restrict__ bq, const float* __restrict__ bk,
                         float* __restrict__ up, float* __restrict__ vp,
                         float* __restrict__ c) {
  const int bx = blockIdx.x;
  if (bx == 32) {
    const int lane = threadIdx.x;
    if (lane >= 64) return;
    float a = 0.f;
#pragma unroll
    for (int i = 0; i < 16; ++i) a += bq[lane * 16 + i] * bk[lane * 16 + i];
#pragma unroll
    for (int off = 32; off > 0; off >>= 1) a += __shfl_xor(a, off);
    if (lane == 0) *c = a;
    return;
  }
  const int echunk = bx & 3;
  const int which = (bx >> 2) & 1;   // 0 -> u (bq.Wk), 1 -> v (bk.Wq)
  const int dchunk = bx >> 3;
  const int d = dchunk * 256 + threadIdx.x;
  const float* W = which ? Wq : Wk;
  const float* bb = which ? bk : bq;
  float acc = 0.f;
  const int e0 = echunk * 256;
#pragma unroll 4
  for (int e = e0; e < e0 + 256; ++e) acc += bb[e] * W[(size_t)e * Dd + d];
  float* dst = which ? vp : up;
  dst[(size_t)echunk * Dd + d] = acc;
}

__global__ void uvc_reduce(const float* __restrict__ up, const float* __restrict__ vp,
                           float* __restrict__ u, float* __restrict__ v) {
  const int d = threadIdx.x;   // block of 1024
  u[d] = (up[d] + up[Dd + d]) + (up[2 * Dd + d] + up[3 * Dd + d]);
  v[d] = (vp[d] + vp[Dd + d]) + (vp[2 * Dd + d] + vp[3 * Dd + d]);
}

// ---------------- fused MFMA kernel ------------------------------------------
// blockIdx.x in [0,8):  dot path  — split GEMM X*G^T (hh+hl+lh), BK=32,
//                       epilogue computes partial x_{s+1}.y_s into pd.
// blockIdx.x in [8,24): norm path — hh GEMM X*[Wq;Wk]^T, BK=64 (32 MFMA per
//                       barrier vs 16; round-4 norm was barrier-drain-bound),
//                       epilogue reduces row sum-of-squares into pn.
// NOTE: (256,2) launch bounds — dot path's accH+accX alone are 128 unified
// regs/thread; (256,4) forces spills (round 2: WRITE 3.4 GB, MfmaUtil 6%).
__global__ __launch_bounds__(256, 2)
void gemm_fused(const _Float16* __restrict__ Ah, const _Float16* __restrict__ Al,
                const _Float16* __restrict__ Gh, const _Float16* __restrict__ Gl,
                const _Float16* __restrict__ Wh,
                const float* __restrict__ X,
                const float* __restrict__ bq, const float* __restrict__ bk,
                float* __restrict__ pd, float* __restrict__ pn) {
  __shared__ __align__(16) _Float16 smem[4 * 128 * 32];   // 32 KB union
  const int tid = threadIdx.x;
  const int wave = tid >> 6, lane = tid & 63;
  const int m0 = blockIdx.y * 128;
  const int wm = (wave >> 1) * 64, wn = (wave & 1) * 64;
  const int fr = lane & 15, g = lane >> 4;

  if (blockIdx.x < 8) {
    // ---------------- dot path (BK=32) ----------------
    _Float16* AsH = smem;
    _Float16* AsL = smem + 4096;
    _Float16* BsH = smem + 8192;
    _Float16* BsL = smem + 12288;
    const int n0 = blockIdx.x * 128;
    const int srow = lane >> 2, c8 = lane & 3;
    f32x4 accH[4][4], accX[4][4];
#pragma unroll
    for (int i = 0; i < 4; ++i)
#pragma unroll
      for (int j = 0; j < 4; ++j) {
        accH[i][j] = (f32x4){0.f, 0.f, 0.f, 0.f};
        accX[i][j] = (f32x4){0.f, 0.f, 0.f, 0.f};
      }
    for (int kt = 0; kt < Kk / 32; ++kt) {
      const int k0 = kt * 32;
#pragma unroll
      for (int it = 0; it < 2; ++it) {
        const int R = wave * 32 + it * 16 + srow;
        const int sg = c8 ^ ((R >> 2) & 3);
        const int ldsoff = (wave * 32 + it * 16) * 32;
        const size_t ga = (size_t)(m0 + R) * Kk + k0 + sg * 8;
        const size_t gb = (size_t)(n0 + R) * Kk + k0 + sg * 8;
        gld_lds16(Ah + ga, &AsH[ldsoff]);
        gld_lds16(Al + ga, &AsL[ldsoff]);
        gld_lds16(Gh + gb, &BsH[ldsoff]);
        gld_lds16(Gl + gb, &BsL[ldsoff]);
      }
      __syncthreads();
      half8 bh[4], bl[4];
#pragma unroll
      for (int j = 0; j < 4; ++j) {
        const int R = wn + 16 * j + fr;
        const int slot = g ^ ((R >> 2) & 3);
        bh[j] = *(const half8*)&BsH[R * 32 + slot * 8];
        bl[j] = *(const half8*)&BsL[R * 32 + slot * 8];
      }
#pragma unroll
      for (int i = 0; i < 4; ++i) {
        const int R = wm + 16 * i + fr;
        const int slot = g ^ ((R >> 2) & 3);
        half8 ah = *(const half8*)&AsH[R * 32 + slot * 8];
        half8 al = *(const half8*)&AsL[R * 32 + slot * 8];
#pragma unroll
        for (int j = 0; j < 4; ++j) {
          accH[i][j] = __builtin_amdgcn_mfma_f32_16x16x32_f16(ah, bh[j], accH[i][j], 0, 0, 0);
          accX[i][j] = __builtin_amdgcn_mfma_f32_16x16x32_f16(ah, bl[j], accX[i][j], 0, 0, 0);
          accX[i][j] = __builtin_amdgcn_mfma_f32_16x16x32_f16(al, bh[j], accX[i][j], 0, 0, 0);
        }
      }
      __syncthreads();
    }
    // epilogue: partial dot d_t += x_t . y_{t-1} over this block's cols
    const int quad = lane >> 4;
    const int slot = blockIdx.x * 2 + (wave & 1);
#pragma unroll
    for (int i = 0; i < 4; ++i) {
#pragma unroll
      for (int r = 0; r < 4; ++r) {
        const int s = m0 + wm + 16 * i + quad * 4 + r;
        const int t = s + 1;
        float dsum = 0.f;
        if ((t & (Ss - 1)) != 0) {
          const float* xrow = X + (size_t)t * Dd + n0 + wn;
#pragma unroll
          for (int j = 0; j < 4; ++j) {
            float yv = accH[i][j][r] + accX[i][j][r] * INV_LO_SCALE;
            dsum += yv * xrow[16 * j + fr];
          }
        }
        dsum += __shfl_xor(dsum, 1);
        dsum += __shfl_xor(dsum, 2);
        dsum += __shfl_xor(dsum, 4);
        dsum += __shfl_xor(dsum, 8);
        if (fr == 0 && ((t & (Ss - 1)) != 0))
          pd[(size_t)slot * Mm + t] = dsum;
      }
    }
  } else {
    // ---------------- norm path (BK=64, hh only) ----------------
    _Float16* NA = smem;            // 128 x 64
    _Float16* NB = smem + 8192;     // 128 x 64
    const int n0 = (blockIdx.x - 8) * 128;
    f32x4 acc[4][4];
#pragma unroll
    for (int i = 0; i < 4; ++i)
#pragma unroll
      for (int j = 0; j < 4; ++j) acc[i][j] = (f32x4){0.f, 0.f, 0.f, 0.f};
    const int srow8 = lane >> 3, s8 = lane & 7;
    for (int kt = 0; kt < Kk / 64; ++kt) {
      const int k0 = kt * 64;
#pragma unroll
      for (int it = 0; it < 4; ++it) {
        const int R = wave * 32 + it * 8 + srow8;
        const int gcol = k0 + ((s8 ^ (R & 7)) * 8);
        const int ldsoff = (wave * 32 + it * 8) * 64;
        gld_lds16(Ah + (size_t)(m0 + R) * Kk + gcol, &NA[ldsoff]);
        gld_lds16(Wh + (size_t)(n0 + R) * Kk + gcol, &NB[ldsoff]);
      }
      __syncthreads();
#pragma unroll
      for (int kk = 0; kk < 2; ++kk) {
        const int gg = kk * 4 + g;
        half8 bh[4];
#pragma unroll
        for (int j = 0; j < 4; ++j) {
          const int R = wn + 16 * j + fr;
          bh[j] = *(const half8*)&NB[R * 64 + (gg ^ (R & 7)) * 8];
        }
#pragma unroll
        for (int i = 0; i < 4; ++i) {
          const int R = wm + 16 * i + fr;
          half8 ah = *(const half8*)&NA[R * 64 + (gg ^ (R & 7)) * 8];
#pragma unroll
          for (int j = 0; j < 4; ++j)
            acc[i][j] = __builtin_amdgcn_mfma_f32_16x16x32_f16(ah, bh[j], acc[i][j], 0, 0, 0);
        }
      }
      __syncthreads();
    }
    const int quad = lane >> 4;
    float bias_j[4];
#pragma unroll
    for (int j = 0; j < 4; ++j) {
      const int n = n0 + wn + 16 * j + fr;
      bias_j[j] = (n < Dd) ? bq[n] : bk[n - Dd];
    }
    const int slot = (blockIdx.x - 8) * 2 + (wave & 1);
#pragma unroll
    for (int i = 0; i < 4; ++i) {
#pragma unroll
      for (int r = 0; r < 4; ++r) {
        float vsum = 0.f;
#pragma unroll
        for (int j = 0; j < 4; ++j) {
          float q = acc[i][j][r] + bias_j[j];
          vsum += q * q;
        }
        vsum += __shfl_xor(vsum, 1);
        vsum += __shfl_xor(vsum, 2);
        vsum += __shfl_xor(vsum, 4);
        vsum += __shfl_xor(vsum, 8);
        if (fr == 0)
          pn[(size_t)slot * Mm + (m0 + wm + 16 * i + quad * 4 + r)] = vsum;
      }
    }
  }
}

// ---------------- final cos / p / b (thread per row) -------------------------
__global__ void cos_final(const float* __restrict__ pd, const float* __restrict__ pn,
                          const float* __restrict__ a_u, const float* __restrict__ a_v,
                          const float* __restrict__ cptr,
                          float* __restrict__ p_out, float* __restrict__ b_out) {
  const int s = blockIdx.x * 256 + threadIdx.x;
  if ((s & (Ss - 1)) == 0) { p_out[s] = 1.0f; b_out[s] = 1.0f; return; }
  float dot = a_u[s - 1] + a_v[s] + *cptr;
#pragma unroll
  for (int sl = 0; sl < 16; ++sl) dot += pd[(size_t)sl * Mm + s];
  float nq = 0.f, nk = 0.f;
#pragma unroll
  for (int sl = 0; sl < 16; ++sl) nq += pn[(size_t)sl * Mm + s];
#pragma unroll
  for (int sl = 16; sl < 32; ++sl) nk += pn[(size_t)sl * Mm + (s - 1)];
  float denom = fmaxf(sqrtf(nq), 1e-8f) * fmaxf(sqrtf(nk), 1e-8f);
  float cs = dot / denom;
  float p = 0.5f * (1.0f - cs);
  p_out[s] = p;
  b_out[s] = (p >= 0.5f) ? 1.0f : 0.0f;
}

// ---------------- per-batch stable scan of flags -----------------------------
__global__ void scan_flags(const float* __restrict__ b_out,
                           int* __restrict__ sel, int* __restrict__ counts) {
  const int b = blockIdx.x;
  const int tid = threadIdx.x;
  const int lane = tid & 63;
  const int w = tid >> 6;
  __shared__ int wtot[4];
  int running = 0;
  for (int c = 0; c < Ss / 256; ++c) {
    const int i = c * 256 + tid;
    const bool f = b_out[b * Ss + i] != 0.0f;
    unsigned long long m = __ballot(f);
    int pre = __popcll(m & ((1ull << lane) - 1ull));
    if (lane == 0) wtot[w] = __popcll(m);
    __syncthreads();
    int woff = 0;
#pragma unroll
    for (int ww = 0; ww < 4; ++ww)
      if (ww < w) woff += wtot[ww];
    int tot = wtot[0] + wtot[1] + wtot[2] + wtot[3];
    if (f) sel[b * Ss + running + woff + pre] = i;
    running += tot;
    __syncthreads();
  }
  if (tid == 0) counts[b] = running;
}

// ---------------- gather selected rows / zero-fill ---------------------------
__global__ void write_out(const float* __restrict__ x, const int* __restrict__ sel,
                          const int* __restrict__ counts, float* __restrict__ out) {
  const int blk = blockIdx.x;
  const int b = blk >> 12;
  const int r = blk & (Ss - 1);
  const int tid = threadIdx.x;
  float4 v = {0.f, 0.f, 0.f, 0.f};
  if (r < counts[b]) {
    const int src = sel[b * Ss + r];
    v = *(const float4*)&x[((size_t)b * Ss + src) * Dd + tid * 4];
  }
  *(float4*)&out[(size_t)blk * Dd + tid * 4] = v;
}

extern "C" void kernel_launch(void* const* d_in, const int* in_sizes, int n_in,
                              void* d_out, int out_size, void* d_ws, size_t ws_size,
                              hipStream_t stream) {
  const float* x  = (const float*)d_in[0];
  const float* Wq = (const float*)d_in[1];
  const float* bq = (const float*)d_in[2];
  const float* Wk = (const float*)d_in[3];
  const float* bk = (const float*)d_in[4];
  float* out = (float*)d_out;

  uint8_t* w = (uint8_t*)d_ws;
  _Float16* Xh = (_Float16*)w;   w += (size_t)Mm * Kk * 2;     // 64 MB
  _Float16* Xl = (_Float16*)w;   w += (size_t)Mm * Kk * 2;     // 64 MB
  float*    Gp = (float*)w;      w += (size_t)4 * Dd * Dd * 4; // 16 MB
  _Float16* Gh = (_Float16*)w;   w += (size_t)Dd * Dd * 2;     // 2 MB
  _Float16* Gl = (_Float16*)w;   w += (size_t)Dd * Dd * 2;     // 2 MB
  _Float16* Wh = (_Float16*)w;   w += (size_t)2 * Dd * Dd * 2; // 4 MB
  float* pd = (float*)w;         w += (size_t)16 * Mm * 4;     // 2 MB
  float* pn = (float*)w;         w += (size_t)32 * Mm * 4;     // 4 MB
  float* a_u = (float*)w;        w += (size_t)Mm * 4;
  float* a_v = (float*)w;        w += (size_t)Mm * 4;
  float* up  = (float*)w;        w += (size_t)4 * Dd * 4;
  float* vp  = (float*)w;        w += (size_t)4 * Dd * 4;
  float* u   = (float*)w;        w += Dd * 4;
  float* v   = (float*)w;        w += Dd * 4;
  float* cpt = (float*)w;        w += 64;
  int*   sel = (int*)w;          w += (size_t)Mm * 4;
  int*   counts = (int*)w;       w += 64;

  float* p_out = out + (size_t)Mm * Dd;
  float* b_out = p_out + Mm;

  // prep (independent of X): G partials, u/v partials, c
  gemm_g_part<<<dim3(16, 16, 4), 256, 0, stream>>>(Wq, Wk, Gp);
  uvc_part<<<33, 256, 0, stream>>>(Wq, Wk, bq, bk, up, vp, cpt);
  uvc_reduce<<<1, 1024, 0, stream>>>(up, vp, u, v);
  // splits
  split_x<<<Mm / 4, 256, 0, stream>>>(x, u, v, Xh, Xl, a_u, a_v);
  split_w3<<<dim3((Dd * Dd / 4) / 256, 3), 256, 0, stream>>>(Gp, Wq, Wk, Gh, Gl, Wh);
  // fused dot+norm MFMA pass
  gemm_fused<<<dim3(24, Mm / 128), 256, 0, stream>>>(Xh, Xl, Gh, Gl, Wh, x, bq, bk, pd, pn);
  // epilogue chain
  cos_final<<<Mm / 256, 256, 0, stream>>>(pd, pn, a_u, a_v, cpt, p_out, b_out);
  scan_flags<<<Bb, 256, 0, stream>>>(b_out, sel, counts);
  write_out<<<Mm, 256, 0, stream>>>(x, sel, counts, out);
}

// Round 6
// 718.704 us; speedup vs baseline: 1.2674x; 1.0879x over previous
//
#include <hip/hip_runtime.h>
#include <stdint.h>

#define Bb 8
#define Ss 4096
#define Dd 1024
#define Mm (Bb*Ss)      // 32768 rows
#define Kk 1024

typedef _Float16 half8 __attribute__((ext_vector_type(8)));
typedef _Float16 half4v __attribute__((ext_vector_type(4)));
typedef float f32x4 __attribute__((ext_vector_type(4)));

#define LO_SCALE 2048.0f
#define INV_LO_SCALE (1.0f/2048.0f)

__device__ __forceinline__ void gld_lds16(const void* g, void* l) {
  __builtin_amdgcn_global_load_lds(
      (const __attribute__((address_space(1))) unsigned int*)g,
      (__attribute__((address_space(3))) unsigned int*)l, 16, 0, 0);
}

// ---------------- split for G(sum of 4 partials) / Wq / Wk -------------------
__global__ void split_w3(const float* __restrict__ Gp, const float* __restrict__ Wq,
                         const float* __restrict__ Wk,
                         _Float16* __restrict__ Gh, _Float16* __restrict__ Gl,
                         _Float16* __restrict__ Wh) {
  const int which = blockIdx.y;
  const int i = blockIdx.x * 256 + threadIdx.x;   // < Dd*Dd/4
  float4 v;
  if (which == 0) {
    float4 v0 = ((const float4*)Gp)[i];
    float4 v1 = ((const float4*)(Gp + (size_t)Dd * Dd))[i];
    float4 v2 = ((const float4*)(Gp + (size_t)2 * Dd * Dd))[i];
    float4 v3 = ((const float4*)(Gp + (size_t)3 * Dd * Dd))[i];
    v.x = (v0.x + v1.x) + (v2.x + v3.x);
    v.y = (v0.y + v1.y) + (v2.y + v3.y);
    v.z = (v0.z + v1.z) + (v2.z + v3.z);
    v.w = (v0.w + v1.w) + (v2.w + v3.w);
  } else {
    const float* src = (which == 1) ? Wq : Wk;
    v = ((const float4*)src)[i];
  }
  _Float16 h0 = (_Float16)v.x, h1 = (_Float16)v.y, h2 = (_Float16)v.z, h3 = (_Float16)v.w;
  if (which == 0) {
    _Float16 l0 = (_Float16)((v.x - (float)h0) * LO_SCALE);
    _Float16 l1 = (_Float16)((v.y - (float)h1) * LO_SCALE);
    _Float16 l2 = (_Float16)((v.z - (float)h2) * LO_SCALE);
    _Float16 l3 = (_Float16)((v.w - (float)h3) * LO_SCALE);
    ((half4v*)Gh)[i] = (half4v){h0, h1, h2, h3};
    ((half4v*)Gl)[i] = (half4v){l0, l1, l2, l3};
  } else {
    _Float16* hi = (which == 1) ? Wh : Wh + (size_t)Dd * Dd;
    ((half4v*)hi)[i] = (half4v){h0, h1, h2, h3};
  }
}

// ------- X split (wave/row) + a_u = u.x, a_v = v.x (u,v summed from partials)
__global__ void split_x(const float* __restrict__ X, const float* __restrict__ up,
                        const float* __restrict__ vp,
                        _Float16* __restrict__ Xh, _Float16* __restrict__ Xl,
                        float* __restrict__ a_u, float* __restrict__ a_v) {
  const int s = blockIdx.x * 4 + (threadIdx.x >> 6);
  const int lane = threadIdx.x & 63;
  float au = 0.f, av = 0.f;
#pragma unroll
  for (int c = 0; c < 4; ++c) {
    const int e = c * 256 + lane * 4;
    float4 xv = *(const float4*)&X[(size_t)s * Dd + e];
    float4 uv = {0.f, 0.f, 0.f, 0.f}, vv = {0.f, 0.f, 0.f, 0.f};
#pragma unroll
    for (int z = 0; z < 4; ++z) {
      float4 a = *(const float4*)&up[(size_t)z * Dd + e];
      float4 b = *(const float4*)&vp[(size_t)z * Dd + e];
      uv.x += a.x; uv.y += a.y; uv.z += a.z; uv.w += a.w;
      vv.x += b.x; vv.y += b.y; vv.z += b.z; vv.w += b.w;
    }
    _Float16 h0 = (_Float16)xv.x, h1 = (_Float16)xv.y, h2 = (_Float16)xv.z, h3 = (_Float16)xv.w;
    _Float16 l0 = (_Float16)((xv.x - (float)h0) * LO_SCALE);
    _Float16 l1 = (_Float16)((xv.y - (float)h1) * LO_SCALE);
    _Float16 l2 = (_Float16)((xv.z - (float)h2) * LO_SCALE);
    _Float16 l3 = (_Float16)((xv.w - (float)h3) * LO_SCALE);
    *(half4v*)&Xh[(size_t)s * Dd + e] = (half4v){h0, h1, h2, h3};
    *(half4v*)&Xl[(size_t)s * Dd + e] = (half4v){l0, l1, l2, l3};
    au += uv.x * xv.x + uv.y * xv.y + uv.z * xv.z + uv.w * xv.w;
    av += vv.x * xv.x + vv.y * xv.y + vv.z * xv.z + vv.w * xv.w;
  }
#pragma unroll
  for (int off = 32; off > 0; off >>= 1) {
    au += __shfl_xor(au, off);
    av += __shfl_xor(av, off);
  }
  if (lane == 0) { a_u[s] = au; a_v[s] = av; }
}

// ------- G partial: Gp[z] = Wq[kz]^T * Wk[kz], K-split x4 (G1: 4 blk/CU) -----
__global__ __launch_bounds__(256)
void gemm_g_part(const float* __restrict__ Wq, const float* __restrict__ Wk,
                 float* __restrict__ Gp) {
  __shared__ float As[16][64];
  __shared__ float Bs[16][64];
  const int t = threadIdx.x;
  const int m0 = blockIdx.y * 64, n0 = blockIdx.x * 64;
  const int kbase = blockIdx.z * 256;
  float acc[4][4];
#pragma unroll
  for (int a = 0; a < 4; ++a)
#pragma unroll
    for (int b = 0; b < 4; ++b) acc[a][b] = 0.f;
  for (int kc = 0; kc < 16; ++kc) {
    const int k0 = kbase + kc * 16;
#pragma unroll
    for (int l = 0; l < 4; ++l) {
      const int idx = l * 256 + t;
      const int kk = idx >> 6, mm = idx & 63;
      As[kk][mm] = Wq[(size_t)(k0 + kk) * Dd + m0 + mm];
      Bs[kk][mm] = Wk[(size_t)(k0 + kk) * Dd + n0 + mm];
    }
    __syncthreads();
    const int tm = (t & 15) * 4, tn = (t >> 4) * 4;
#pragma unroll
    for (int k = 0; k < 16; ++k) {
      float4 a4 = *(const float4*)&As[k][tm];
      float4 b4 = *(const float4*)&Bs[k][tn];
      const float aa[4] = {a4.x, a4.y, a4.z, a4.w};
      const float bb[4] = {b4.x, b4.y, b4.z, b4.w};
#pragma unroll
      for (int a = 0; a < 4; ++a)
#pragma unroll
        for (int b = 0; b < 4; ++b) acc[a][b] += aa[a] * bb[b];
    }
    __syncthreads();
  }
  float* dst = Gp + (size_t)blockIdx.z * Dd * Dd;
  const int tm = (t & 15) * 4, tn = (t >> 4) * 4;
#pragma unroll
  for (int a = 0; a < 4; ++a)
#pragma unroll
    for (int b = 0; b < 4; ++b)
      dst[(size_t)(m0 + tm + a) * Dd + n0 + tn + b] = acc[a][b];
}

// ------- u/v partials over e-chunks (32 blocks) + c (block 32) ---------------
__global__ void uvc_part(const float* __restrict__ Wq, const float* __restrict__ Wk,
                         const float* __restrict__ bq, const float* __restrict__ bk,
                         float* __restrict__ up, float* __restrict__ vp,
                         float* __restrict__ c) {
  const int bx = blockIdx.x;
  if (bx == 32) {
    const int lane = threadIdx.x;
    if (lane >= 64) return;
    float a = 0.f;
#pragma unroll
    for (int i = 0; i < 16; ++i) a += bq[lane * 16 + i] * bk[lane * 16 + i];
#pragma unroll
    for (int off = 32; off > 0; off >>= 1) a += __shfl_xor(a, off);
    if (lane == 0) *c = a;
    return;
  }
  const int echunk = bx & 3;
  const int which = (bx >> 2) & 1;   // 0 -> u (bq.Wk), 1 -> v (bk.Wq)
  const int dchunk = bx >> 3;
  const int d = dchunk * 256 + threadIdx.x;
  const float* W = which ? Wq : Wk;
  const float* bb = which ? bk : bq;
  float acc = 0.f;
  const int e0 = echunk * 256;
#pragma unroll 4
  for (int e = e0; e < e0 + 256; ++e) acc += bb[e] * W[(size_t)e * Dd + d];
  float* dst = which ? vp : up;
  dst[(size_t)echunk * Dd + d] = acc;
}

// ---------------- dot GEMM: split X*G^T, BK=64, epilogue -> pd ---------------
// (256,2): accH+accX = 128 unified regs/thread; tighter bounds spill (round 2).
// BK=64: 96 MFMA per barrier (was 48) — halves the per-kt vmcnt(0) drains.
__global__ __launch_bounds__(256, 2)
void gemm_dot(const _Float16* __restrict__ Ah, const _Float16* __restrict__ Al,
              const _Float16* __restrict__ Gh, const _Float16* __restrict__ Gl,
              const float* __restrict__ X, float* __restrict__ pd) {
  __shared__ __align__(16) _Float16 smem[4 * 128 * 64];   // 64 KB
  _Float16* AsH = smem;
  _Float16* AsL = smem + 8192;
  _Float16* BsH = smem + 16384;
  _Float16* BsL = smem + 24576;
  const int tid = threadIdx.x;
  const int wave = tid >> 6, lane = tid & 63;
  const int m0 = blockIdx.y * 128, n0 = blockIdx.x * 128;
  const int wm = (wave >> 1) * 64, wn = (wave & 1) * 64;
  const int fr = lane & 15, g = lane >> 4;
  const int srow8 = lane >> 3, s8 = lane & 7;

  f32x4 accH[4][4], accX[4][4];
#pragma unroll
  for (int i = 0; i < 4; ++i)
#pragma unroll
    for (int j = 0; j < 4; ++j) {
      accH[i][j] = (f32x4){0.f, 0.f, 0.f, 0.f};
      accX[i][j] = (f32x4){0.f, 0.f, 0.f, 0.f};
    }

  for (int kt = 0; kt < Kk / 64; ++kt) {
    const int k0 = kt * 64;
#pragma unroll
    for (int it = 0; it < 4; ++it) {
      const int R = wave * 32 + it * 8 + srow8;
      const int gcol = k0 + ((s8 ^ (R & 7)) * 8);
      const int ldsoff = (wave * 32 + it * 8) * 64;   // wave-uniform base
      const size_t ga = (size_t)(m0 + R) * Kk + gcol;
      const size_t gb = (size_t)(n0 + R) * Kk + gcol;
      gld_lds16(Ah + ga, &AsH[ldsoff]);
      gld_lds16(Al + ga, &AsL[ldsoff]);
      gld_lds16(Gh + gb, &BsH[ldsoff]);
      gld_lds16(Gl + gb, &BsL[ldsoff]);
    }
    __syncthreads();
#pragma unroll
    for (int kk = 0; kk < 2; ++kk) {
      const int gg = kk * 4 + g;
      half8 bh[4], bl[4];
#pragma unroll
      for (int j = 0; j < 4; ++j) {
        const int R = wn + 16 * j + fr;
        const int sl = (gg ^ (R & 7)) * 8;
        bh[j] = *(const half8*)&BsH[R * 64 + sl];
        bl[j] = *(const half8*)&BsL[R * 64 + sl];
      }
#pragma unroll
      for (int i = 0; i < 4; ++i) {
        const int R = wm + 16 * i + fr;
        const int sl = (gg ^ (R & 7)) * 8;
        half8 ah = *(const half8*)&AsH[R * 64 + sl];
        half8 al = *(const half8*)&AsL[R * 64 + sl];
#pragma unroll
        for (int j = 0; j < 4; ++j) {
          accH[i][j] = __builtin_amdgcn_mfma_f32_16x16x32_f16(ah, bh[j], accH[i][j], 0, 0, 0);
          accX[i][j] = __builtin_amdgcn_mfma_f32_16x16x32_f16(ah, bl[j], accX[i][j], 0, 0, 0);
          accX[i][j] = __builtin_amdgcn_mfma_f32_16x16x32_f16(al, bh[j], accX[i][j], 0, 0, 0);
        }
      }
    }
    __syncthreads();
  }
  // epilogue: partial dot d_t += x_t . y_{t-1} over this block's cols
  const int quad = lane >> 4;
  const int slot = blockIdx.x * 2 + (wave & 1);
#pragma unroll
  for (int i = 0; i < 4; ++i) {
#pragma unroll
    for (int r = 0; r < 4; ++r) {
      const int s = m0 + wm + 16 * i + quad * 4 + r;
      const int t = s + 1;
      float dsum = 0.f;
      if ((t & (Ss - 1)) != 0) {
        const float* xrow = X + (size_t)t * Dd + n0 + wn;
#pragma unroll
        for (int j = 0; j < 4; ++j) {
          float yv = accH[i][j][r] + accX[i][j][r] * INV_LO_SCALE;
          dsum += yv * xrow[16 * j + fr];
        }
      }
      dsum += __shfl_xor(dsum, 1);
      dsum += __shfl_xor(dsum, 2);
      dsum += __shfl_xor(dsum, 4);
      dsum += __shfl_xor(dsum, 8);
      if (fr == 0 && ((t & (Ss - 1)) != 0))
        pd[(size_t)slot * Mm + t] = dsum;
    }
  }
}

// ---------------- norm GEMM: hh X*[Wq;Wk]^T, BK=64, epilogue -> pn -----------
// (256,3): ~70 VGPR + 64 AGPR < 170 budget -> 3 waves/SIMD (fusion had capped
// this path at the dot path's 2 waves/SIMD — the round-4/5 regression).
__global__ __launch_bounds__(256, 3)
void gemm_norm(const _Float16* __restrict__ Ah, const _Float16* __restrict__ Wh,
               const float* __restrict__ bq, const float* __restrict__ bk,
               float* __restrict__ pn) {
  __shared__ __align__(16) _Float16 smem[2 * 128 * 64];   // 32 KB
  _Float16* NA = smem;
  _Float16* NB = smem + 8192;
  const int tid = threadIdx.x;
  const int wave = tid >> 6, lane = tid & 63;
  const int m0 = blockIdx.y * 128, n0 = blockIdx.x * 128;
  const int wm = (wave >> 1) * 64, wn = (wave & 1) * 64;
  const int fr = lane & 15, g = lane >> 4;
  const int srow8 = lane >> 3, s8 = lane & 7;

  f32x4 acc[4][4];
#pragma unroll
  for (int i = 0; i < 4; ++i)
#pragma unroll
    for (int j = 0; j < 4; ++j) acc[i][j] = (f32x4){0.f, 0.f, 0.f, 0.f};

  for (int kt = 0; kt < Kk / 64; ++kt) {
    const int k0 = kt * 64;
#pragma unroll
    for (int it = 0; it < 4; ++it) {
      const int R = wave * 32 + it * 8 + srow8;
      const int gcol = k0 + ((s8 ^ (R & 7)) * 8);
      const int ldsoff = (wave * 32 + it * 8) * 64;
      gld_lds16(Ah + (size_t)(m0 + R) * Kk + gcol, &NA[ldsoff]);
      gld_lds16(Wh + (size_t)(n0 + R) * Kk + gcol, &NB[ldsoff]);
    }
    __syncthreads();
#pragma unroll
    for (int kk = 0; kk < 2; ++kk) {
      const int gg = kk * 4 + g;
      half8 bh[4];
#pragma unroll
      for (int j = 0; j < 4; ++j) {
        const int R = wn + 16 * j + fr;
        bh[j] = *(const half8*)&NB[R * 64 + (gg ^ (R & 7)) * 8];
      }
#pragma unroll
      for (int i = 0; i < 4; ++i) {
        const int R = wm + 16 * i + fr;
        half8 ah = *(const half8*)&NA[R * 64 + (gg ^ (R & 7)) * 8];
#pragma unroll
        for (int j = 0; j < 4; ++j)
          acc[i][j] = __builtin_amdgcn_mfma_f32_16x16x32_f16(ah, bh[j], acc[i][j], 0, 0, 0);
      }
    }
    __syncthreads();
  }
  const int quad = lane >> 4;
  float bias_j[4];
#pragma unroll
  for (int j = 0; j < 4; ++j) {
    const int n = n0 + wn + 16 * j + fr;
    bias_j[j] = (n < Dd) ? bq[n] : bk[n - Dd];
  }
  const int slot = blockIdx.x * 2 + (wave & 1);
#pragma unroll
  for (int i = 0; i < 4; ++i) {
#pragma unroll
    for (int r = 0; r < 4; ++r) {
      float vsum = 0.f;
#pragma unroll
      for (int j = 0; j < 4; ++j) {
        float q = acc[i][j][r] + bias_j[j];
        vsum += q * q;
      }
      vsum += __shfl_xor(vsum, 1);
      vsum += __shfl_xor(vsum, 2);
      vsum += __shfl_xor(vsum, 4);
      vsum += __shfl_xor(vsum, 8);
      if (fr == 0)
        pn[(size_t)slot * Mm + (m0 + wm + 16 * i + quad * 4 + r)] = vsum;
    }
  }
}

// ---------------- final cos / p / b (thread per row) -------------------------
__global__ void cos_final(const float* __restrict__ pd, const float* __restrict__ pn,
                          const float* __restrict__ a_u, const float* __restrict__ a_v,
                          const float* __restrict__ cptr,
                          float* __restrict__ p_out, float* __restrict__ b_out) {
  const int s = blockIdx.x * 256 + threadIdx.x;
  if ((s & (Ss - 1)) == 0) { p_out[s] = 1.0f; b_out[s] = 1.0f; return; }
  float dot = a_u[s - 1] + a_v[s] + *cptr;
#pragma unroll
  for (int sl = 0; sl < 16; ++sl) dot += pd[(size_t)sl * Mm + s];
  float nq = 0.f, nk = 0.f;
#pragma unroll
  for (int sl = 0; sl < 16; ++sl) nq += pn[(size_t)sl * Mm + s];
#pragma unroll
  for (int sl = 16; sl < 32; ++sl) nk += pn[(size_t)sl * Mm + (s - 1)];
  float denom = fmaxf(sqrtf(nq), 1e-8f) * fmaxf(sqrtf(nk), 1e-8f);
  float cs = dot / denom;
  float p = 0.5f * (1.0f - cs);
  p_out[s] = p;
  b_out[s] = (p >= 0.5f) ? 1.0f : 0.0f;
}

// ---------------- per-batch stable scan of flags (1024 thr, 4 chunks) --------
__global__ __launch_bounds__(1024)
void scan_flags(const float* __restrict__ b_out,
                int* __restrict__ sel, int* __restrict__ counts) {
  const int b = blockIdx.x;
  const int tid = threadIdx.x;
  const int lane = tid & 63;
  const int w = tid >> 6;          // 16 waves
  __shared__ int wtot[16];
  float fv[4];
#pragma unroll
  for (int c = 0; c < 4; ++c) fv[c] = b_out[b * Ss + c * 1024 + tid];
  int running = 0;
#pragma unroll
  for (int c = 0; c < 4; ++c) {
    const bool f = fv[c] != 0.0f;
    unsigned long long m = __ballot(f);
    int pre = __popcll(m & ((1ull << lane) - 1ull));
    if (lane == 0) wtot[w] = __popcll(m);
    __syncthreads();
    int woff = 0, tot = 0;
#pragma unroll
    for (int ww = 0; ww < 16; ++ww) {
      int t = wtot[ww];
      if (ww < w) woff += t;
      tot += t;
    }
    if (f) sel[b * Ss + running + woff + pre] = c * 1024 + tid;
    running += tot;
    __syncthreads();
  }
  if (tid == 0) counts[b] = running;
}

// ---------------- gather selected rows / zero-fill ---------------------------
__global__ void write_out(const float* __restrict__ x, const int* __restrict__ sel,
                          const int* __restrict__ counts, float* __restrict__ out) {
  const int blk = blockIdx.x;
  const int b = blk >> 12;
  const int r = blk & (Ss - 1);
  const int tid = threadIdx.x;
  float4 v = {0.f, 0.f, 0.f, 0.f};
  if (r < counts[b]) {
    const int src = sel[b * Ss + r];
    v = *(const float4*)&x[((size_t)b * Ss + src) * Dd + tid * 4];
  }
  *(float4*)&out[(size_t)blk * Dd + tid * 4] = v;
}

extern "C" void kernel_launch(void* const* d_in, const int* in_sizes, int n_in,
                              void* d_out, int out_size, void* d_ws, size_t ws_size,
                              hipStream_t stream) {
  const float* x  = (const float*)d_in[0];
  const float* Wq = (const float*)d_in[1];
  const float* bq = (const float*)d_in[2];
  const float* Wk = (const float*)d_in[3];
  const float* bk = (const float*)d_in[4];
  float* out = (float*)d_out;

  uint8_t* w = (uint8_t*)d_ws;
  _Float16* Xh = (_Float16*)w;   w += (size_t)Mm * Kk * 2;     // 64 MB
  _Float16* Xl = (_Float16*)w;   w += (size_t)Mm * Kk * 2;     // 64 MB
  float*    Gp = (float*)w;      w += (size_t)4 * Dd * Dd * 4; // 16 MB
  _Float16* Gh = (_Float16*)w;   w += (size_t)Dd * Dd * 2;     // 2 MB
  _Float16* Gl = (_Float16*)w;   w += (size_t)Dd * Dd * 2;     // 2 MB
  _Float16* Wh = (_Float16*)w;   w += (size_t)2 * Dd * Dd * 2; // 4 MB
  float* pd = (float*)w;         w += (size_t)16 * Mm * 4;     // 2 MB
  float* pn = (float*)w;         w += (size_t)32 * Mm * 4;     // 4 MB
  float* a_u = (float*)w;        w += (size_t)Mm * 4;
  float* a_v = (float*)w;        w += (size_t)Mm * 4;
  float* up  = (float*)w;        w += (size_t)4 * Dd * 4;
  float* vp  = (float*)w;        w += (size_t)4 * Dd * 4;
  float* cpt = (float*)w;        w += 64;
  int*   sel = (int*)w;          w += (size_t)Mm * 4;
  int*   counts = (int*)w;       w += 64;

  float* p_out = out + (size_t)Mm * Dd;
  float* b_out = p_out + Mm;

  // prep (independent of X): G partials, u/v partials, c
  gemm_g_part<<<dim3(16, 16, 4), 256, 0, stream>>>(Wq, Wk, Gp);
  uvc_part<<<33, 256, 0, stream>>>(Wq, Wk, bq, bk, up, vp, cpt);
  // splits
  split_x<<<Mm / 4, 256, 0, stream>>>(x, up, vp, Xh, Xl, a_u, a_v);
  split_w3<<<dim3((Dd * Dd / 4) / 256, 3), 256, 0, stream>>>(Gp, Wq, Wk, Gh, Gl, Wh);
  // MFMA passes (separate kernels: norm runs at 3 waves/SIMD)
  gemm_norm<<<dim3(2 * Dd / 128, Mm / 128), 256, 0, stream>>>(Xh, Wh, bq, bk, pn);
  gemm_dot<<<dim3(Dd / 128, Mm / 128), 256, 0, stream>>>(Xh, Xl, Gh, Gl, x, pd);
  // epilogue chain
  cos_final<<<Mm / 256, 256, 0, stream>>>(pd, pn, a_u, a_v, cpt, p_out, b_out);
  scan_flags<<<Bb, 1024, 0, stream>>>(b_out, sel, counts);
  write_out<<<Mm, 256, 0, stream>>>(x, sel, counts, out);
}